// Round 11
// baseline (348.371 us; speedup 1.0000x reference)
//
#include <hip/hip_runtime.h>

typedef unsigned short USH;
typedef short s16x8 __attribute__((ext_vector_type(8)));
typedef float f32x4 __attribute__((ext_vector_type(4)));
typedef float f32x4v __attribute__((ext_vector_type(4)));
typedef unsigned int u32x4 __attribute__((ext_vector_type(4)));
// may_alias variants for ALL type-punned LDS/global accesses.
typedef s16x8 s16x8_a __attribute__((may_alias));
typedef f32x4v f32x4v_a __attribute__((may_alias));
typedef u32x4 u32x4_a __attribute__((may_alias));
typedef unsigned long long u64_a __attribute__((may_alias));

#if __has_builtin(__builtin_amdgcn_exp2f)
#define EXP2F(x) __builtin_amdgcn_exp2f(x)  // raw v_exp_f32, no legalization
#else
#define EXP2F(x) __builtin_exp2f(x)
#endif

__device__ __forceinline__ USH f2bf(float f) {
  union { float f; unsigned int i; } c; c.f = f;
  unsigned int x = c.i;
  return (USH)((x + 0x7FFFu + ((x >> 16) & 1u)) >> 16);
}
__device__ __forceinline__ unsigned int pk_bf16(float a, float b) {
#if __has_builtin(__builtin_amdgcn_cvt_pk_bf16_f32)
  typedef USH ush2 __attribute__((ext_vector_type(2)));
  union { ush2 v; unsigned int u; } r;
  r.v = __builtin_amdgcn_cvt_pk_bf16_f32(a, b);
  return r.u;
#else
  union { float f; unsigned int i; } ca, cb; ca.f = a; cb.f = b;
  return ((ca.i + 0x8000u) >> 16) | ((cb.i + 0x8000u) & 0xFFFF0000u);
#endif
}

__device__ __forceinline__ f32x4 mfma16(s16x8 a, s16x8 b, f32x4 c) {
  return __builtin_amdgcn_mfma_f32_16x16x32_bf16(a, b, c, 0, 0, 0);
}

// ------------- weight transpose + fp32->bf16: WT[n][k] = bf16(W[k][n]) -------------
__global__ void transpose_w(const float* __restrict__ Wq, const float* __restrict__ Wk,
                            const float* __restrict__ Wv, const float* __restrict__ Wo,
                            USH* __restrict__ wsT) {
  __shared__ float tile[32][33];
  const int z = blockIdx.z;
  const float* W = (z == 0) ? Wq : (z == 1) ? Wk : (z == 2) ? Wv : Wo;
  USH* WT = wsT + (size_t)z * 262144;
  const int n0 = blockIdx.x * 32, k0 = blockIdx.y * 32;
  const int tx = threadIdx.x, ty = threadIdx.y;  // 32 x 8
  #pragma unroll
  for (int i = 0; i < 4; ++i)
    tile[ty + i * 8][tx] = W[(size_t)(k0 + ty + i * 8) * 512 + n0 + tx];
  __syncthreads();
  #pragma unroll
  for (int i = 0; i < 4; ++i)
    WT[(size_t)(n0 + ty + i * 8) * 512 + k0 + tx] = f2bf(tile[tx][ty + i * 8]);
}

// ---------------- x fp32 -> bf16 (one-shot, so GEMM stages bf16 A) ----------------
__global__ __launch_bounds__(256) void cvt_x(const float* __restrict__ x,
                                             USH* __restrict__ xb) {
  const size_t i = ((size_t)blockIdx.x * 256 + threadIdx.x) * 8;
  const f32x4v a = *(const f32x4v_a*)(x + i);
  const f32x4v b = *(const f32x4v_a*)(x + i + 4);
  u32x4 s;
  s.x = pk_bf16(a.x, a.y); s.y = pk_bf16(a.z, a.w);
  s.z = pk_bf16(b.x, b.y); s.w = pk_bf16(b.z, b.w);
  *(u32x4_a*)(xb + i) = s;
}

// ---------------- GEMM: out = A[M,512](bf16) * WT^T + bias ----------------
// MODE 0: float out[m*512+n] (d_out fp32).
// MODE 1: z==0 -> Q bf16 [B,H,S,Hd] scaled by sc*log2e; z==1 -> K [B,H,S,Hd];
//         z==2 -> V [B,H,Hd,S] (pre-transposed for attn).
// Round-9 proven structure: single-buffer, 2 barriers, register prefetch.
template <int MODE>
__global__ __launch_bounds__(256, 2) void gemm_bias(
    const USH* __restrict__ A, const USH* __restrict__ BT0,
    const float* __restrict__ b0, const float* __restrict__ b1,
    const float* __restrict__ b2,
    USH* __restrict__ oQ, USH* __restrict__ oKV, float* __restrict__ oF) {
  __shared__ __align__(16) USH As[128 * 36];
  __shared__ __align__(16) USH Bs[128 * 36];
  const int z = blockIdx.z;
  const USH* BT = BT0 + (size_t)z * 262144;
  const float* bias = (z == 0) ? b0 : ((z == 1) ? b1 : b2);
  USH* outb = (z == 0) ? oQ : (oKV + (size_t)(z - 1) * 4194304);
  const float qs = (MODE == 1 && z == 0) ? 0.06375871528132839f : 1.0f;

  const int t = threadIdx.x;
  const int w = t >> 6, lane = t & 63;
  const int c = lane & 15, g = lane >> 4;
  const int wm = w & 1, wn = w >> 1;
  const int m0 = blockIdx.x * 128, n0 = blockIdx.y * 128;
  const int srow = t >> 1, scol = (t & 1) * 16;  // staging: 128 rows x 2 halves

  f32x4 acc[4][4] = {};

  const USH* Ap0 = A + (size_t)(m0 + srow) * 512 + scol;
  const USH* Bp0 = BT + (size_t)(n0 + srow) * 512 + scol;
  s16x8 pa0 = *(const s16x8_a*)(Ap0);
  s16x8 pa1 = *(const s16x8_a*)(Ap0 + 8);
  s16x8 pb0 = *(const s16x8_a*)(Bp0);
  s16x8 pb1 = *(const s16x8_a*)(Bp0 + 8);

  for (int kt = 0; kt < 16; ++kt) {
    __syncthreads();
    *(s16x8_a*)(As + srow * 36 + scol) = pa0;
    *(s16x8_a*)(As + srow * 36 + scol + 8) = pa1;
    *(s16x8_a*)(Bs + srow * 36 + scol) = pb0;
    *(s16x8_a*)(Bs + srow * 36 + scol + 8) = pb1;
    // prefetch tile kt+1 (latency hides under this tile's compute)
    const int ktn = (kt < 15) ? kt + 1 : kt;
    pa0 = *(const s16x8_a*)(Ap0 + ktn * 32);
    pa1 = *(const s16x8_a*)(Ap0 + ktn * 32 + 8);
    pb0 = *(const s16x8_a*)(Bp0 + ktn * 32);
    pb1 = *(const s16x8_a*)(Bp0 + ktn * 32 + 8);
    __syncthreads();
    s16x8 af[4], bfr[4];
    #pragma unroll
    for (int i = 0; i < 4; ++i) {
      af[i]  = *(const s16x8_a*)(As + (wm * 64 + i * 16 + c) * 36 + g * 8);
      bfr[i] = *(const s16x8_a*)(Bs + (wn * 64 + i * 16 + c) * 36 + g * 8);
    }
    #pragma unroll
    for (int mf = 0; mf < 4; ++mf)
      #pragma unroll
      for (int nf = 0; nf < 4; ++nf)
        acc[mf][nf] = mfma16(af[mf], bfr[nf], acc[mf][nf]);
  }

  #pragma unroll
  for (int nf = 0; nf < 4; ++nf) {
    const int n = n0 + wn * 64 + nf * 16 + c;
    const float bv = bias[n];
    #pragma unroll
    for (int mf = 0; mf < 4; ++mf)
      #pragma unroll
      for (int r = 0; r < 4; ++r) {
        const int m = m0 + wm * 64 + mf * 16 + g * 4 + r;
        const float v = (acc[mf][nf][r] + bv) * qs;
        if (MODE == 0) {
          oF[(size_t)m * 512 + n] = v;  // fp32 store
        } else {
          const int bb = m >> 12, s = m & 4095, h = n >> 6, hd = n & 63;
          if (z == 2)  // V transposed: [B,H,Hd,S]
            outb[(((size_t)(bb * 8 + h)) * 64 + hd) * 4096 + s] = f2bf(v);
          else
            outb[(((size_t)(bb * 8 + h)) * 4096 + s) * 64 + hd] = f2bf(v);
        }
      }
  }
}

// ---------------- flash attention v6: BARRIER-FREE K-loop ----------------
// grid: (32 q-tiles, 16 bh). block 256 = 4 waves, each wave owns 32 q-rows.
// Key insight: the MFMA fragment layouts for K (S^T A-operand) and pre-transposed
// V (PV B-operand) are 16B-contiguous in GLOBAL memory -> load fragments directly,
// no LDS staging, no __syncthreads in the loop. Each 128B cache line is exactly one
// K row / V key-pair-chunk, consumed fully; 4 waves/block share lines via L1.
// Only LDS use: per-wave Ps (P C-layout -> A-layout transpose) + l broadcast.
// Q pre-scaled by sc*log2e -> p = exp2(s). l = P.1 on the MFMA pipe.
__global__ __launch_bounds__(256, 2) void attn(const USH* __restrict__ Qbuf,
                                               const USH* __restrict__ kv,
                                               USH* __restrict__ att) {
  __shared__ __align__(16) USH Ps[4][32 * 76];  // per-wave [32 qrow][76 key-pad]
  __shared__ float lbuf[4][32];                 // per-wave l broadcast

  const int t = threadIdx.x;
  const int w = t >> 6, lane = t & 63;
  const int c = lane & 15, g = lane >> 4;
  const int bh = blockIdx.y;
  const int bb = bh >> 3, hh = bh & 7;
  const size_t base = (size_t)bh * 262144;  // 4096*64
  const USH* Q = Qbuf + base;
  const USH* K = kv + base;                 // [S,Hd]
  const USH* V = kv + 4194304 + base;       // [Hd,S] (pre-transposed)
  const int q0 = blockIdx.x * 128 + w * 32;

  // Q fragments (B-operand of S^T): registers for the whole K loop
  s16x8 qf[2][2];
  #pragma unroll
  for (int colf = 0; colf < 2; ++colf)
    #pragma unroll
    for (int kh = 0; kh < 2; ++kh)
      qf[colf][kh] = *(const s16x8_a*)(Q + (size_t)(q0 + colf * 16 + c) * 64 + kh * 32 + g * 8);

  // constant ones-column B-fragment: B[k][n]=1.0bf16 iff n==0 -> D[m][0]=sum_k A[m][k]
  s16x8 onesf;
  {
    const short one = (short)0x3F80, val = (c == 0) ? one : (short)0;
    #pragma unroll
    for (int j = 0; j < 8; ++j) onesf[j] = val;
  }

  f32x4 o[2][4] = {};
  f32x4 o_l[2] = {};
  // per-lane fragment base pointers
  const USH* Kp = K + (size_t)c * 64 + g * 8;          // + (kt*64+kff*16)*64 + kh*32
  const USH* Vp = V + (size_t)c * 4096 + g * 8;        // + hf*16*4096 + kt*64 + kf*32

  for (int kt = 0; kt < 64; ++kt) {
    // S^T[key][qrow] = K * Q^T -- K fragments straight from global (L1-resident)
    f32x4 st[4][2] = {};
    #pragma unroll
    for (int kh = 0; kh < 2; ++kh) {
      s16x8 ak[4];
      #pragma unroll
      for (int kff = 0; kff < 4; ++kff)
        ak[kff] = *(const s16x8_a*)(Kp + (size_t)(kt * 64 + kff * 16) * 64 + kh * 32);
      #pragma unroll
      for (int kff = 0; kff < 4; ++kff)
        #pragma unroll
        for (int colf = 0; colf < 2; ++colf)
          st[kff][colf] = mfma16(ak[kff], qf[colf][kh], st[kff][colf]);
    }

    // p = exp2(s)  (Q pre-scaled; denominator comes from the MFMA ones-column)
    #pragma unroll
    for (int colf = 0; colf < 2; ++colf)
      #pragma unroll
      for (int kff = 0; kff < 4; ++kff)
        #pragma unroll
        for (int r = 0; r < 4; ++r)
          st[kff][colf][r] = EXP2F(st[kff][colf][r]);

    // write P to Ps[w][qrow][key] (wave-local; in-order DS, no barrier needed)
    #pragma unroll
    for (int colf = 0; colf < 2; ++colf)
      #pragma unroll
      for (int kff = 0; kff < 4; ++kff) {
        const unsigned int lo = pk_bf16(st[kff][colf][0], st[kff][colf][1]);
        const unsigned int hi = pk_bf16(st[kff][colf][2], st[kff][colf][3]);
        const unsigned long long pk64 =
            (unsigned long long)lo | ((unsigned long long)hi << 32);
        *(u64_a*)(&Ps[w][(c + 16 * colf) * 76 + kff * 16 + g * 4]) = pk64;
      }

    // O[qrow][hd] += P * V ; l[qrow] += P . 1 -- V fragments straight from global
    #pragma unroll
    for (int kf = 0; kf < 2; ++kf) {
      s16x8 ap[2], bv[4];
      #pragma unroll
      for (int mf = 0; mf < 2; ++mf)
        ap[mf] = *(const s16x8_a*)(&Ps[w][(mf * 16 + c) * 76 + kf * 32 + g * 8]);
      #pragma unroll
      for (int hf = 0; hf < 4; ++hf)
        bv[hf] = *(const s16x8_a*)(Vp + (size_t)hf * 16 * 4096 + kt * 64 + kf * 32);
      #pragma unroll
      for (int mf = 0; mf < 2; ++mf) {
        #pragma unroll
        for (int hf = 0; hf < 4; ++hf)
          o[mf][hf] = mfma16(ap[mf], bv[hf], o[mf][hf]);
        o_l[mf] = mfma16(ap[mf], onesf, o_l[mf]);
      }
    }
  }

  // l lives in lanes c==0 (D[m][0]); broadcast within the wave via LDS
  if (c == 0) {
    #pragma unroll
    for (int mf = 0; mf < 2; ++mf)
      #pragma unroll
      for (int r = 0; r < 4; ++r)
        lbuf[w][mf * 16 + g * 4 + r] = o_l[mf][r];
  }
  __syncthreads();

  #pragma unroll
  for (int mf = 0; mf < 2; ++mf)
    #pragma unroll
    for (int r = 0; r < 4; ++r) {
      const int ml = mf * 16 + g * 4 + r;
      const float linv = 1.0f / lbuf[w][ml];
      const int qrow = q0 + ml;
      #pragma unroll
      for (int hf = 0; hf < 4; ++hf) {
        const int hd = c + 16 * hf;
        att[((size_t)(bb * 4096 + qrow)) * 512 + hh * 64 + hd] =
            f2bf(o[mf][hf][r] * linv);
      }
    }
}

extern "C" void kernel_launch(void* const* d_in, const int* in_sizes, int n_in,
                              void* d_out, int out_size, void* d_ws, size_t ws_size,
                              hipStream_t stream) {
  (void)in_sizes; (void)n_in; (void)out_size; (void)ws_size;
  const float* x  = (const float*)d_in[0];
  const float* Wq = (const float*)d_in[1];
  const float* bq = (const float*)d_in[2];
  const float* Wk = (const float*)d_in[3];
  const float* bk = (const float*)d_in[4];
  const float* Wv = (const float*)d_in[5];
  const float* bv = (const float*)d_in[6];
  const float* Wo = (const float*)d_in[7];
  const float* bo = (const float*)d_in[8];
  USH* ws  = (USH*)d_ws;
  USH* wT  = ws;                       // 4 * 262144 bf16 transposed weights (2 MB)
  USH* kv  = ws + 1048576;             // K [B,H,S,Hd] + V [B,H,Hd,S] bf16 (16 MB)
  USH* att = ws + 1048576 + 8388608;   // 4194304 : attn out [B,S,D] bf16 (8 MB)
  float* outF = (float*)d_out;         // fp32 output (16 MB)
  USH* qscratch = (USH*)d_out;         // Q bf16 (8 MB), dead before final GEMM
  USH* xb = (USH*)d_out + 4194304;     // x bf16 (8 MB), dead before final GEMM

  transpose_w<<<dim3(16, 16, 4), dim3(32, 8), 0, stream>>>(Wq, Wk, Wv, Wo, wT);
  cvt_x<<<2048, 256, 0, stream>>>(x, xb);
  gemm_bias<1><<<dim3(64, 4, 3), 256, 0, stream>>>(xb, wT, bq, bk, bv,
                                                   qscratch, kv, nullptr);
  attn<<<dim3(32, 16), 256, 0, stream>>>(qscratch, kv, att);
  gemm_bias<0><<<dim3(64, 4, 1), 256, 0, stream>>>(att, wT + 3 * 262144, bo, bo, bo,
                                                   nullptr, nullptr, outF);
}

// Round 12
// 248.638 us; speedup vs baseline: 1.4011x; 1.4011x over previous
//
#include <hip/hip_runtime.h>

typedef unsigned short USH;
typedef short s16x8 __attribute__((ext_vector_type(8)));
typedef float f32x4 __attribute__((ext_vector_type(4)));
typedef float f32x4v __attribute__((ext_vector_type(4)));
typedef unsigned int u32x4 __attribute__((ext_vector_type(4)));
// may_alias variants for ALL type-punned LDS/global accesses.
typedef s16x8 s16x8_a __attribute__((may_alias));
typedef f32x4v f32x4v_a __attribute__((may_alias));
typedef u32x4 u32x4_a __attribute__((may_alias));
typedef unsigned long long u64_a __attribute__((may_alias));

#if __has_builtin(__builtin_amdgcn_exp2f)
#define EXP2F(x) __builtin_amdgcn_exp2f(x)  // raw v_exp_f32, no legalization
#else
#define EXP2F(x) __builtin_exp2f(x)
#endif

__device__ __forceinline__ USH f2bf(float f) {
  union { float f; unsigned int i; } c; c.f = f;
  unsigned int x = c.i;
  return (USH)((x + 0x7FFFu + ((x >> 16) & 1u)) >> 16);
}
__device__ __forceinline__ unsigned int pk_bf16(float a, float b) {
#if __has_builtin(__builtin_amdgcn_cvt_pk_bf16_f32)
  typedef USH ush2 __attribute__((ext_vector_type(2)));
  union { ush2 v; unsigned int u; } r;
  r.v = __builtin_amdgcn_cvt_pk_bf16_f32(a, b);
  return r.u;
#else
  union { float f; unsigned int i; } ca, cb; ca.f = a; cb.f = b;
  return ((ca.i + 0x8000u) >> 16) | ((cb.i + 0x8000u) & 0xFFFF0000u);
#endif
}

__device__ __forceinline__ f32x4 mfma16(s16x8 a, s16x8 b, f32x4 c) {
  return __builtin_amdgcn_mfma_f32_16x16x32_bf16(a, b, c, 0, 0, 0);
}

// ------------- weight transpose + fp32->bf16: WT[n][k] = bf16(W[k][n]) -------------
__global__ void transpose_w(const float* __restrict__ Wq, const float* __restrict__ Wk,
                            const float* __restrict__ Wv, const float* __restrict__ Wo,
                            USH* __restrict__ wsT) {
  __shared__ float tile[32][33];
  const int z = blockIdx.z;
  const float* W = (z == 0) ? Wq : (z == 1) ? Wk : (z == 2) ? Wv : Wo;
  USH* WT = wsT + (size_t)z * 262144;
  const int n0 = blockIdx.x * 32, k0 = blockIdx.y * 32;
  const int tx = threadIdx.x, ty = threadIdx.y;  // 32 x 8
  #pragma unroll
  for (int i = 0; i < 4; ++i)
    tile[ty + i * 8][tx] = W[(size_t)(k0 + ty + i * 8) * 512 + n0 + tx];
  __syncthreads();
  #pragma unroll
  for (int i = 0; i < 4; ++i)
    WT[(size_t)(n0 + ty + i * 8) * 512 + k0 + tx] = f2bf(tile[tx][ty + i * 8]);
}

// ---------------- x fp32 -> bf16 (one-shot, so GEMM stages bf16 A) ----------------
__global__ __launch_bounds__(256) void cvt_x(const float* __restrict__ x,
                                             USH* __restrict__ xb) {
  const size_t i = ((size_t)blockIdx.x * 256 + threadIdx.x) * 8;
  const f32x4v a = *(const f32x4v_a*)(x + i);
  const f32x4v b = *(const f32x4v_a*)(x + i + 4);
  u32x4 s;
  s.x = pk_bf16(a.x, a.y); s.y = pk_bf16(a.z, a.w);
  s.z = pk_bf16(b.x, b.y); s.w = pk_bf16(b.z, b.w);
  *(u32x4_a*)(xb + i) = s;
}

// ---------------- GEMM: out = A[M,512](bf16) * WT^T + bias ----------------
// MODE 0: float out[m*512+n] (d_out fp32).
// MODE 1: z==0 -> Q bf16 [B,H,S,Hd] scaled by sc*log2e; z==1 -> K [B,H,S,Hd];
//         z==2 -> V [B,H,Hd,S] (pre-transposed for attn).
// BK=64 (8 K-iters, half the barriers), register prefetch, 3 blocks/CU
// (QKV grid=768 -> single-pass residency; (256,2) left 256 blocks in a tail pass).
// LDS rows padded to 68 USH (34 dwords, 2-way max = free).
template <int MODE>
__global__ __launch_bounds__(256, 3) void gemm_bias(
    const USH* __restrict__ A, const USH* __restrict__ BT0,
    const float* __restrict__ b0, const float* __restrict__ b1,
    const float* __restrict__ b2,
    USH* __restrict__ oQ, USH* __restrict__ oKV, float* __restrict__ oF) {
  __shared__ __align__(16) USH As[128 * 68];
  __shared__ __align__(16) USH Bs[128 * 68];
  const int z = blockIdx.z;
  const USH* BT = BT0 + (size_t)z * 262144;
  const float* bias = (z == 0) ? b0 : ((z == 1) ? b1 : b2);
  USH* outb = (z == 0) ? oQ : (oKV + (size_t)(z - 1) * 4194304);
  const float qs = (MODE == 1 && z == 0) ? 0.06375871528132839f : 1.0f;

  const int t = threadIdx.x;
  const int w = t >> 6, lane = t & 63;
  const int c = lane & 15, g = lane >> 4;
  const int wm = w & 1, wn = w >> 1;
  const int m0 = blockIdx.x * 128, n0 = blockIdx.y * 128;
  const int srow = t >> 1, scol = (t & 1) * 32;  // staging: 128 rows x 2 half-rows of 32

  f32x4 acc[4][4] = {};

  const USH* Ap0 = A + (size_t)(m0 + srow) * 512 + scol;
  const USH* Bp0 = BT + (size_t)(n0 + srow) * 512 + scol;
  s16x8 pa[4], pb[4];
  #pragma unroll
  for (int j = 0; j < 4; ++j) {
    pa[j] = *(const s16x8_a*)(Ap0 + j * 8);
    pb[j] = *(const s16x8_a*)(Bp0 + j * 8);
  }

  for (int kt = 0; kt < 8; ++kt) {
    __syncthreads();
    #pragma unroll
    for (int j = 0; j < 4; ++j) {
      *(s16x8_a*)(As + srow * 68 + scol + j * 8) = pa[j];
      *(s16x8_a*)(Bs + srow * 68 + scol + j * 8) = pb[j];
    }
    // prefetch tile kt+1 (latency hides under this tile's compute)
    const int ktn = (kt < 7) ? kt + 1 : kt;
    #pragma unroll
    for (int j = 0; j < 4; ++j) {
      pa[j] = *(const s16x8_a*)(Ap0 + ktn * 64 + j * 8);
      pb[j] = *(const s16x8_a*)(Bp0 + ktn * 64 + j * 8);
    }
    __syncthreads();
    #pragma unroll
    for (int ks = 0; ks < 2; ++ks) {
      s16x8 af[4], bfr[4];
      #pragma unroll
      for (int i = 0; i < 4; ++i) {
        af[i]  = *(const s16x8_a*)(As + (wm * 64 + i * 16 + c) * 68 + ks * 32 + g * 8);
        bfr[i] = *(const s16x8_a*)(Bs + (wn * 64 + i * 16 + c) * 68 + ks * 32 + g * 8);
      }
      #pragma unroll
      for (int mf = 0; mf < 4; ++mf)
        #pragma unroll
        for (int nf = 0; nf < 4; ++nf)
          acc[mf][nf] = mfma16(af[mf], bfr[nf], acc[mf][nf]);
    }
  }

  #pragma unroll
  for (int nf = 0; nf < 4; ++nf) {
    const int n = n0 + wn * 64 + nf * 16 + c;
    const float bv = bias[n];
    #pragma unroll
    for (int mf = 0; mf < 4; ++mf)
      #pragma unroll
      for (int r = 0; r < 4; ++r) {
        const int m = m0 + wm * 64 + mf * 16 + g * 4 + r;
        const float v = (acc[mf][nf][r] + bv) * qs;
        if (MODE == 0) {
          oF[(size_t)m * 512 + n] = v;  // fp32 store
        } else {
          const int bb = m >> 12, s = m & 4095, h = n >> 6, hd = n & 63;
          if (z == 2)  // V transposed: [B,H,Hd,S]
            outb[(((size_t)(bb * 8 + h)) * 64 + hd) * 4096 + s] = f2bf(v);
          else
            outb[(((size_t)(bb * 8 + h)) * 4096 + s) * 64 + hd] = f2bf(v);
        }
      }
  }
}

// ---------------- flash attention v7 ----------------
// grid: (32 q-tiles, 16 bh). block 256 = 4 waves, each wave owns 32 q-rows.
// K staged in LDS (all 4 waves read IDENTICAL K fragments -> 4x traffic saving),
// with register prefetch (round-9 proven). V (pre-transposed, fragments 16B
// global-contiguous) lives in per-wave registers with distance-1 prefetch:
// V(kt+1) loads issue after PV(kt), wait lands under S^T+exp of kt+1.
// (Round 11 showed distance-0 direct-global exposes full latency: 243us.)
// Q pre-scaled by sc*log2e -> p = exp2(s). l = P.1 on the MFMA pipe.
__global__ __launch_bounds__(256, 2) void attn(const USH* __restrict__ Qbuf,
                                               const USH* __restrict__ kv,
                                               USH* __restrict__ att) {
  __shared__ __align__(16) USH Ks[2 * 64 * 36];  // [half][key][36]
  __shared__ __align__(16) USH Ps[4][32 * 76];   // per-wave [32 qrow][76 key-pad]
  __shared__ float lbuf[4][32];                  // per-wave l broadcast

  const int t = threadIdx.x;
  const int w = t >> 6, lane = t & 63;
  const int c = lane & 15, g = lane >> 4;
  const int bh = blockIdx.y;
  const int bb = bh >> 3, hh = bh & 7;
  const size_t base = (size_t)bh * 262144;  // 4096*64
  const USH* Q = Qbuf + base;
  const USH* K = kv + base;                 // [S,Hd]
  const USH* V = kv + 4194304 + base;       // [Hd,S] (pre-transposed)
  const int q0 = blockIdx.x * 128 + w * 32;

  // Q fragments (B-operand of S^T): registers for the whole K loop
  s16x8 qf[2][2];
  #pragma unroll
  for (int colf = 0; colf < 2; ++colf)
    #pragma unroll
    for (int kh = 0; kh < 2; ++kh)
      qf[colf][kh] = *(const s16x8_a*)(Q + (size_t)(q0 + colf * 16 + c) * 64 + kh * 32 + g * 8);

  // constant ones-column B-fragment: B[k][n]=1.0bf16 iff n==0 -> D[m][0]=sum_k A[m][k]
  s16x8 onesf;
  {
    const short one = (short)0x3F80, val = (c == 0) ? one : (short)0;
    #pragma unroll
    for (int j = 0; j < 8; ++j) onesf[j] = val;
  }

  f32x4 o[2][4] = {};
  f32x4 o_l[2] = {};
  const int kr = t >> 2, kc = (t & 3) * 16;  // K staging coords (row, col16)
  const USH* Kp0 = K + (size_t)kr * 64 + kc;    // + kt*4096
  const int khalf = kc >> 5, koff = kc & 31;
  const USH* Vp = V + (size_t)c * 4096 + g * 8;  // + hf*16*4096 + kt*64 + kf*32

  // prefetch tile 0: K (staging regs) + V (fragment regs)
  s16x8 pk0 = *(const s16x8_a*)(Kp0);
  s16x8 pk1 = *(const s16x8_a*)(Kp0 + 8);
  s16x8 pv[2][4];
  #pragma unroll
  for (int kf = 0; kf < 2; ++kf)
    #pragma unroll
    for (int hf = 0; hf < 4; ++hf)
      pv[kf][hf] = *(const s16x8_a*)(Vp + (size_t)hf * 65536 + kf * 32);

  for (int kt = 0; kt < 64; ++kt) {
    __syncthreads();
    *(s16x8_a*)(Ks + khalf * 2304 + kr * 36 + koff) = pk0;
    *(s16x8_a*)(Ks + khalf * 2304 + kr * 36 + koff + 8) = pk1;
    // prefetch K tile kt+1 (hides under compute below)
    const int ktn = (kt < 63) ? kt + 1 : kt;
    pk0 = *(const s16x8_a*)(Kp0 + (size_t)ktn * 4096);
    pk1 = *(const s16x8_a*)(Kp0 + (size_t)ktn * 4096 + 8);
    __syncthreads();

    // S^T[key][qrow] = K * Q^T   (Q pre-scaled; st IS the exp2 argument)
    f32x4 st[4][2] = {};
    #pragma unroll
    for (int kh = 0; kh < 2; ++kh) {
      s16x8 ak[4];
      #pragma unroll
      for (int kff = 0; kff < 4; ++kff)
        ak[kff] = *(const s16x8_a*)(Ks + kh * 2304 + (kff * 16 + c) * 36 + g * 8);
      #pragma unroll
      for (int kff = 0; kff < 4; ++kff)
        #pragma unroll
        for (int colf = 0; colf < 2; ++colf)
          st[kff][colf] = mfma16(ak[kff], qf[colf][kh], st[kff][colf]);
    }

    // p = exp2(s)  (denominator comes from the MFMA ones-column, not VALU)
    #pragma unroll
    for (int colf = 0; colf < 2; ++colf)
      #pragma unroll
      for (int kff = 0; kff < 4; ++kff)
        #pragma unroll
        for (int r = 0; r < 4; ++r)
          st[kff][colf][r] = EXP2F(st[kff][colf][r]);

    // write P to Ps[w][qrow][key] (wave-local; in-order DS, no barrier needed)
    #pragma unroll
    for (int colf = 0; colf < 2; ++colf)
      #pragma unroll
      for (int kff = 0; kff < 4; ++kff) {
        const unsigned int lo = pk_bf16(st[kff][colf][0], st[kff][colf][1]);
        const unsigned int hi = pk_bf16(st[kff][colf][2], st[kff][colf][3]);
        const unsigned long long pk64 =
            (unsigned long long)lo | ((unsigned long long)hi << 32);
        *(u64_a*)(&Ps[w][(c + 16 * colf) * 76 + kff * 16 + g * 4]) = pk64;
      }

    // O[qrow][hd] += P * V ; l[qrow] += P . 1 (V from prefetched registers)
    #pragma unroll
    for (int kf = 0; kf < 2; ++kf) {
      s16x8 ap[2];
      #pragma unroll
      for (int mf = 0; mf < 2; ++mf)
        ap[mf] = *(const s16x8_a*)(&Ps[w][(mf * 16 + c) * 76 + kf * 32 + g * 8]);
      #pragma unroll
      for (int mf = 0; mf < 2; ++mf) {
        #pragma unroll
        for (int hf = 0; hf < 4; ++hf)
          o[mf][hf] = mfma16(ap[mf], pv[kf][hf], o[mf][hf]);
        o_l[mf] = mfma16(ap[mf], onesf, o_l[mf]);
      }
    }
    // prefetch V fragments for kt+1 (consumed above; wait hides under next S^T+exp)
    #pragma unroll
    for (int kf = 0; kf < 2; ++kf)
      #pragma unroll
      for (int hf = 0; hf < 4; ++hf)
        pv[kf][hf] = *(const s16x8_a*)(Vp + (size_t)hf * 65536 + ktn * 64 + kf * 32);
  }

  // l lives in lanes c==0 (D[m][0]); broadcast within the wave via LDS
  if (c == 0) {
    #pragma unroll
    for (int mf = 0; mf < 2; ++mf)
      #pragma unroll
      for (int r = 0; r < 4; ++r)
        lbuf[w][mf * 16 + g * 4 + r] = o_l[mf][r];
  }
  __syncthreads();

  #pragma unroll
  for (int mf = 0; mf < 2; ++mf)
    #pragma unroll
    for (int r = 0; r < 4; ++r) {
      const int ml = mf * 16 + g * 4 + r;
      const float linv = 1.0f / lbuf[w][ml];
      const int qrow = q0 + ml;
      #pragma unroll
      for (int hf = 0; hf < 4; ++hf) {
        const int hd = c + 16 * hf;
        att[((size_t)(bb * 4096 + qrow)) * 512 + hh * 64 + hd] =
            f2bf(o[mf][hf][r] * linv);
      }
    }
}

extern "C" void kernel_launch(void* const* d_in, const int* in_sizes, int n_in,
                              void* d_out, int out_size, void* d_ws, size_t ws_size,
                              hipStream_t stream) {
  (void)in_sizes; (void)n_in; (void)out_size; (void)ws_size;
  const float* x  = (const float*)d_in[0];
  const float* Wq = (const float*)d_in[1];
  const float* bq = (const float*)d_in[2];
  const float* Wk = (const float*)d_in[3];
  const float* bk = (const float*)d_in[4];
  const float* Wv = (const float*)d_in[5];
  const float* bv = (const float*)d_in[6];
  const float* Wo = (const float*)d_in[7];
  const float* bo = (const float*)d_in[8];
  USH* ws  = (USH*)d_ws;
  USH* wT  = ws;                       // 4 * 262144 bf16 transposed weights (2 MB)
  USH* kv  = ws + 1048576;             // K [B,H,S,Hd] + V [B,H,Hd,S] bf16 (16 MB)
  USH* att = ws + 1048576 + 8388608;   // 4194304 : attn out [B,S,D] bf16 (8 MB)
  float* outF = (float*)d_out;         // fp32 output (16 MB)
  USH* qscratch = (USH*)d_out;         // Q bf16 (8 MB), dead before final GEMM
  USH* xb = (USH*)d_out + 4194304;     // x bf16 (8 MB), dead before final GEMM

  transpose_w<<<dim3(16, 16, 4), dim3(32, 8), 0, stream>>>(Wq, Wk, Wv, Wo, wT);
  cvt_x<<<2048, 256, 0, stream>>>(x, xb);
  gemm_bias<1><<<dim3(64, 4, 3), 256, 0, stream>>>(xb, wT, bq, bk, bv,
                                                   qscratch, kv, nullptr);
  attn<<<dim3(32, 16), 256, 0, stream>>>(qscratch, kv, att);
  gemm_bias<0><<<dim3(64, 4, 1), 256, 0, stream>>>(att, wT + 3 * 262144, bo, bo, bo,
                                                   nullptr, nullptr, outF);
}

// Round 13
// 213.569 us; speedup vs baseline: 1.6312x; 1.1642x over previous
//
#include <hip/hip_runtime.h>

typedef unsigned short USH;
typedef short s16x8 __attribute__((ext_vector_type(8)));
typedef float f32x4 __attribute__((ext_vector_type(4)));
typedef float f32x4v __attribute__((ext_vector_type(4)));
typedef unsigned int u32x4 __attribute__((ext_vector_type(4)));
// may_alias variants for ALL type-punned LDS/global accesses.
typedef s16x8 s16x8_a __attribute__((may_alias));
typedef f32x4v f32x4v_a __attribute__((may_alias));
typedef u32x4 u32x4_a __attribute__((may_alias));
typedef unsigned long long u64_a __attribute__((may_alias));

#if __has_builtin(__builtin_amdgcn_exp2f)
#define EXP2F(x) __builtin_amdgcn_exp2f(x)  // raw v_exp_f32, no legalization
#else
#define EXP2F(x) __builtin_exp2f(x)
#endif

__device__ __forceinline__ USH f2bf(float f) {
  union { float f; unsigned int i; } c; c.f = f;
  unsigned int x = c.i;
  return (USH)((x + 0x7FFFu + ((x >> 16) & 1u)) >> 16);
}
__device__ __forceinline__ unsigned int pk_bf16(float a, float b) {
#if __has_builtin(__builtin_amdgcn_cvt_pk_bf16_f32)
  typedef USH ush2 __attribute__((ext_vector_type(2)));
  union { ush2 v; unsigned int u; } r;
  r.v = __builtin_amdgcn_cvt_pk_bf16_f32(a, b);
  return r.u;
#else
  union { float f; unsigned int i; } ca, cb; ca.f = a; cb.f = b;
  return ((ca.i + 0x8000u) >> 16) | ((cb.i + 0x8000u) & 0xFFFF0000u);
#endif
}

__device__ __forceinline__ f32x4 mfma16(s16x8 a, s16x8 b, f32x4 c) {
  return __builtin_amdgcn_mfma_f32_16x16x32_bf16(a, b, c, 0, 0, 0);
}

// async global->LDS, 16B per lane; LDS dest semantics: wave base + lane*16.
#if __has_builtin(__builtin_amdgcn_global_load_lds)
#define HAS_GLD 1
__device__ __forceinline__ void gld_lds16(const USH* g, USH* l) {
  __builtin_amdgcn_global_load_lds(
      static_cast<const unsigned int __attribute__((address_space(1)))*>(
          (const void __attribute__((address_space(1)))*)g),
      static_cast<unsigned int __attribute__((address_space(3)))*>(
          (void __attribute__((address_space(3)))*)l),
      16, 0, 0);
}
#else
#define HAS_GLD 0
__device__ __forceinline__ void gld_lds16(const USH* g, USH* l) {
  *(s16x8_a*)l = *(const s16x8_a*)g;  // fallback: synchronous copy, same addresses
}
#endif

// ------------- weight transpose + fp32->bf16: WT[n][k] = bf16(W[k][n]) -------------
__global__ void transpose_w(const float* __restrict__ Wq, const float* __restrict__ Wk,
                            const float* __restrict__ Wv, const float* __restrict__ Wo,
                            USH* __restrict__ wsT) {
  __shared__ float tile[32][33];
  const int z = blockIdx.z;
  const float* W = (z == 0) ? Wq : (z == 1) ? Wk : (z == 2) ? Wv : Wo;
  USH* WT = wsT + (size_t)z * 262144;
  const int n0 = blockIdx.x * 32, k0 = blockIdx.y * 32;
  const int tx = threadIdx.x, ty = threadIdx.y;  // 32 x 8
  #pragma unroll
  for (int i = 0; i < 4; ++i)
    tile[ty + i * 8][tx] = W[(size_t)(k0 + ty + i * 8) * 512 + n0 + tx];
  __syncthreads();
  #pragma unroll
  for (int i = 0; i < 4; ++i)
    WT[(size_t)(n0 + ty + i * 8) * 512 + k0 + tx] = f2bf(tile[tx][ty + i * 8]);
}

// ---------------- x fp32 -> bf16 (one-shot, so GEMM stages bf16 A) ----------------
__global__ __launch_bounds__(256) void cvt_x(const float* __restrict__ x,
                                             USH* __restrict__ xb) {
  const size_t i = ((size_t)blockIdx.x * 256 + threadIdx.x) * 8;
  const f32x4v a = *(const f32x4v_a*)(x + i);
  const f32x4v b = *(const f32x4v_a*)(x + i + 4);
  u32x4 s;
  s.x = pk_bf16(a.x, a.y); s.y = pk_bf16(a.z, a.w);
  s.z = pk_bf16(b.x, b.y); s.w = pk_bf16(b.z, b.w);
  *(u32x4_a*)(xb + i) = s;
}

// ---------------- GEMM: out = A[M,512](bf16) * WT^T + bias ----------------
// MODE 0: float out[m*512+n] (d_out fp32).
// MODE 1: z==0 -> Q bf16 [B,H,S,Hd] scaled by sc*log2e; z==1 -> K [B,H,S,Hd];
//         z==2 -> V [B,H,Hd,S] (pre-transposed for attn).
// BK=64, register prefetch, 3 blocks/CU (768-block QKV dispatch single-pass).
template <int MODE>
__global__ __launch_bounds__(256, 3) void gemm_bias(
    const USH* __restrict__ A, const USH* __restrict__ BT0,
    const float* __restrict__ b0, const float* __restrict__ b1,
    const float* __restrict__ b2,
    USH* __restrict__ oQ, USH* __restrict__ oKV, float* __restrict__ oF) {
  __shared__ __align__(16) USH As[128 * 68];
  __shared__ __align__(16) USH Bs[128 * 68];
  const int z = blockIdx.z;
  const USH* BT = BT0 + (size_t)z * 262144;
  const float* bias = (z == 0) ? b0 : ((z == 1) ? b1 : b2);
  USH* outb = (z == 0) ? oQ : (oKV + (size_t)(z - 1) * 4194304);
  const float qs = (MODE == 1 && z == 0) ? 0.06375871528132839f : 1.0f;

  const int t = threadIdx.x;
  const int w = t >> 6, lane = t & 63;
  const int c = lane & 15, g = lane >> 4;
  const int wm = w & 1, wn = w >> 1;
  const int m0 = blockIdx.x * 128, n0 = blockIdx.y * 128;
  const int srow = t >> 1, scol = (t & 1) * 32;

  f32x4 acc[4][4] = {};

  const USH* Ap0 = A + (size_t)(m0 + srow) * 512 + scol;
  const USH* Bp0 = BT + (size_t)(n0 + srow) * 512 + scol;
  s16x8 pa[4], pb[4];
  #pragma unroll
  for (int j = 0; j < 4; ++j) {
    pa[j] = *(const s16x8_a*)(Ap0 + j * 8);
    pb[j] = *(const s16x8_a*)(Bp0 + j * 8);
  }

  for (int kt = 0; kt < 8; ++kt) {
    __syncthreads();
    #pragma unroll
    for (int j = 0; j < 4; ++j) {
      *(s16x8_a*)(As + srow * 68 + scol + j * 8) = pa[j];
      *(s16x8_a*)(Bs + srow * 68 + scol + j * 8) = pb[j];
    }
    const int ktn = (kt < 7) ? kt + 1 : kt;
    #pragma unroll
    for (int j = 0; j < 4; ++j) {
      pa[j] = *(const s16x8_a*)(Ap0 + ktn * 64 + j * 8);
      pb[j] = *(const s16x8_a*)(Bp0 + ktn * 64 + j * 8);
    }
    __syncthreads();
    #pragma unroll
    for (int ks = 0; ks < 2; ++ks) {
      s16x8 af[4], bfr[4];
      #pragma unroll
      for (int i = 0; i < 4; ++i) {
        af[i]  = *(const s16x8_a*)(As + (wm * 64 + i * 16 + c) * 68 + ks * 32 + g * 8);
        bfr[i] = *(const s16x8_a*)(Bs + (wn * 64 + i * 16 + c) * 68 + ks * 32 + g * 8);
      }
      #pragma unroll
      for (int mf = 0; mf < 4; ++mf)
        #pragma unroll
        for (int nf = 0; nf < 4; ++nf)
          acc[mf][nf] = mfma16(af[mf], bfr[nf], acc[mf][nf]);
    }
  }

  #pragma unroll
  for (int nf = 0; nf < 4; ++nf) {
    const int n = n0 + wn * 64 + nf * 16 + c;
    const float bv = bias[n];
    #pragma unroll
    for (int mf = 0; mf < 4; ++mf)
      #pragma unroll
      for (int r = 0; r < 4; ++r) {
        const int m = m0 + wm * 64 + mf * 16 + g * 4 + r;
        const float v = (acc[mf][nf][r] + bv) * qs;
        if (MODE == 0) {
          oF[(size_t)m * 512 + n] = v;
        } else {
          const int bb = m >> 12, s = m & 4095, h = n >> 6, hd = n & 63;
          if (z == 2)
            outb[(((size_t)(bb * 8 + h)) * 64 + hd) * 4096 + s] = f2bf(v);
          else
            outb[(((size_t)(bb * 8 + h)) * 4096 + s) * 64 + hd] = f2bf(v);
        }
      }
  }
}

// ---------------- flash attention v8: async-DMA double-buffered staging ----------------
// grid: (32 q-tiles, 16 bh). block 256 = 4 waves, each wave owns 32 q-rows.
// K/V staged via global_load_lds into XOR-swizzled LDS (DMA needs base+lane*16,
// i.e. no padding; swizzle gives <=2-way banked reads = free):
//   K [half][key][64B]: chunk stored at q = cc ^ ((key>>1)&3)
//   V [hd][128B]:       chunk stored at q = cc ^ (hd&7)
// Double-buffered: DMA for tile kt+1 issues right after the (single) barrier and
// flies for a full compute iteration; barrier's implicit vmcnt(0) waits exactly
// for tile kt. One barrier/iter. Compute identical to round 9 (same absmax).
__global__ __launch_bounds__(256, 2) void attn(const USH* __restrict__ Qbuf,
                                               const USH* __restrict__ kv,
                                               USH* __restrict__ att) {
  __shared__ __align__(16) USH Ks[2 * 4096];   // [buf][half][64 key][32 USH]
  __shared__ __align__(16) USH Vt[2 * 4096];   // [buf][64 hd][64 USH]
  __shared__ __align__(16) USH Ps[4][32 * 76]; // per-wave [32 qrow][76 key-pad]
  __shared__ float lbuf[4][32];

  const int t = threadIdx.x;
  const int w = t >> 6, lane = t & 63;
  const int c = lane & 15, g = lane >> 4;
  const int bh = blockIdx.y;
  const int bb = bh >> 3, hh = bh & 7;
  const size_t base = (size_t)bh * 262144;  // 4096*64
  const USH* Q = Qbuf + base;
  const USH* K = kv + base;                 // [S,Hd]
  const USH* V = kv + 4194304 + base;       // [Hd,S] (pre-transposed)
  const int q0 = blockIdx.x * 128 + w * 32;

  // Q fragments (B-operand of S^T): registers for the whole K loop
  s16x8 qf[2][2];
  #pragma unroll
  for (int colf = 0; colf < 2; ++colf)
    #pragma unroll
    for (int kh = 0; kh < 2; ++kh)
      qf[colf][kh] = *(const s16x8_a*)(Q + (size_t)(q0 + colf * 16 + c) * 64 + kh * 32 + g * 8);

  // constant ones-column B-fragment: l = P . 1 on the MFMA pipe
  s16x8 onesf;
  {
    const short one = (short)0x3F80, val = (c == 0) ? one : (short)0;
    #pragma unroll
    for (int j = 0; j < 8; ++j) onesf[j] = val;
  }

  f32x4 o[2][4] = {};
  f32x4 o_l[2] = {};

  // --- DMA lane mappings (wave w stages rows [w*16, w*16+16)) ---
  // K: lane l -> row rK = w*16 + (l>>2), phys chunk l&3, global chunk ccK
  const int rK = w * 16 + (lane >> 2);
  const int ccK = (lane & 3) ^ ((lane >> 3) & 3);
  const USH* gK0 = K + (size_t)rK * 64 + ccK * 8;        // half0; +32 for half1; +kt*4096
  // V: lane l -> hd = w*16 + p*8 + (l>>3), phys chunk l&7, global chunk ccV
  const int hdV = w * 16 + (lane >> 3);
  const int ccV = (lane & 7) ^ ((lane >> 3) & 7);
  const USH* gV0 = V + (size_t)hdV * 4096 + ccV * 8;           // p=0; +kt*64
  const USH* gV1 = V + (size_t)(hdV + 8) * 4096 + ccV * 8;     // p=1
  USH* lK = Ks + w * 512 + lane * 8;      // +buf*4096, +2048 for half1
  USH* lV = Vt + w * 1024 + lane * 8;     // +buf*4096, +512 for p=1

  // issue tile 0 -> buf 0
  gld_lds16(gK0, lK);
  gld_lds16(gK0 + 32, lK + 2048);
  gld_lds16(gV0, lV);
  gld_lds16(gV1, lV + 512);

  for (int kt = 0; kt < 64; ++kt) {
    const int buf = kt & 1;
    __syncthreads();  // implicit vmcnt(0): tile kt resident; buf^1 free to overwrite
    if (kt < 63) {    // issue tile kt+1 -> buf^1; flies across this whole iteration
      const int nb = (buf ^ 1) * 4096;
      const size_t kof = (size_t)(kt + 1) * 4096;
      const size_t vof = (size_t)(kt + 1) * 64;
      gld_lds16(gK0 + kof, lK + nb);
      gld_lds16(gK0 + 32 + kof, lK + nb + 2048);
      gld_lds16(gV0 + vof, lV + nb);
      gld_lds16(gV1 + vof, lV + nb + 512);
    }

    // S^T[key][qrow] = K * Q^T  (Q pre-scaled; st IS the exp2 argument)
    f32x4 st[4][2] = {};
    #pragma unroll
    for (int kh = 0; kh < 2; ++kh) {
      s16x8 ak[4];
      #pragma unroll
      for (int kff = 0; kff < 4; ++kff) {
        const int row = kff * 16 + c;
        const int qsw = (g ^ ((c >> 1) & 3)) * 8;  // K swizzle: (row>>1)&3 == (c>>1)&3
        ak[kff] = *(const s16x8_a*)(Ks + buf * 4096 + kh * 2048 + row * 32 + qsw);
      }
      #pragma unroll
      for (int kff = 0; kff < 4; ++kff)
        #pragma unroll
        for (int colf = 0; colf < 2; ++colf)
          st[kff][colf] = mfma16(ak[kff], qf[colf][kh], st[kff][colf]);
    }

    // p = exp2(s)
    #pragma unroll
    for (int colf = 0; colf < 2; ++colf)
      #pragma unroll
      for (int kff = 0; kff < 4; ++kff)
        #pragma unroll
        for (int r = 0; r < 4; ++r)
          st[kff][colf][r] = EXP2F(st[kff][colf][r]);

    // write P to Ps[w][qrow][key] (wave-local; in-order DS, no barrier)
    #pragma unroll
    for (int colf = 0; colf < 2; ++colf)
      #pragma unroll
      for (int kff = 0; kff < 4; ++kff) {
        const unsigned int lo = pk_bf16(st[kff][colf][0], st[kff][colf][1]);
        const unsigned int hi = pk_bf16(st[kff][colf][2], st[kff][colf][3]);
        const unsigned long long pk64 =
            (unsigned long long)lo | ((unsigned long long)hi << 32);
        *(u64_a*)(&Ps[w][(c + 16 * colf) * 76 + kff * 16 + g * 4]) = pk64;
      }

    // O[qrow][hd] += P * V ; l[qrow] += P . 1
    #pragma unroll
    for (int kf = 0; kf < 2; ++kf) {
      s16x8 ap[2], bv[4];
      #pragma unroll
      for (int mf = 0; mf < 2; ++mf)
        ap[mf] = *(const s16x8_a*)(&Ps[w][(mf * 16 + c) * 76 + kf * 32 + g * 8]);
      #pragma unroll
      for (int hf = 0; hf < 4; ++hf) {
        const int qv = ((kf * 4 + g) ^ (c & 7)) * 8;  // V swizzle: hd&7 == c&7
        bv[hf] = *(const s16x8_a*)(Vt + buf * 4096 + (c + 16 * hf) * 64 + qv);
      }
      #pragma unroll
      for (int mf = 0; mf < 2; ++mf) {
        #pragma unroll
        for (int hf = 0; hf < 4; ++hf)
          o[mf][hf] = mfma16(ap[mf], bv[hf], o[mf][hf]);
        o_l[mf] = mfma16(ap[mf], onesf, o_l[mf]);
      }
    }
  }

  // l lives in lanes c==0 (D[m][0]); broadcast within the wave via LDS
  if (c == 0) {
    #pragma unroll
    for (int mf = 0; mf < 2; ++mf)
      #pragma unroll
      for (int r = 0; r < 4; ++r)
        lbuf[w][mf * 16 + g * 4 + r] = o_l[mf][r];
  }
  __syncthreads();

  #pragma unroll
  for (int mf = 0; mf < 2; ++mf)
    #pragma unroll
    for (int r = 0; r < 4; ++r) {
      const int ml = mf * 16 + g * 4 + r;
      const float linv = 1.0f / lbuf[w][ml];
      const int qrow = q0 + ml;
      #pragma unroll
      for (int hf = 0; hf < 4; ++hf) {
        const int hd = c + 16 * hf;
        att[((size_t)(bb * 4096 + qrow)) * 512 + hh * 64 + hd] =
            f2bf(o[mf][hf][r] * linv);
      }
    }
}

extern "C" void kernel_launch(void* const* d_in, const int* in_sizes, int n_in,
                              void* d_out, int out_size, void* d_ws, size_t ws_size,
                              hipStream_t stream) {
  (void)in_sizes; (void)n_in; (void)out_size; (void)ws_size;
  const float* x  = (const float*)d_in[0];
  const float* Wq = (const float*)d_in[1];
  const float* bq = (const float*)d_in[2];
  const float* Wk = (const float*)d_in[3];
  const float* bk = (const float*)d_in[4];
  const float* Wv = (const float*)d_in[5];
  const float* bv = (const float*)d_in[6];
  const float* Wo = (const float*)d_in[7];
  const float* bo = (const float*)d_in[8];
  USH* ws  = (USH*)d_ws;
  USH* wT  = ws;                       // 4 * 262144 bf16 transposed weights (2 MB)
  USH* kv  = ws + 1048576;             // K [B,H,S,Hd] + V [B,H,Hd,S] bf16 (16 MB)
  USH* att = ws + 1048576 + 8388608;   // 4194304 : attn out [B,S,D] bf16 (8 MB)
  float* outF = (float*)d_out;         // fp32 output (16 MB)
  USH* qscratch = (USH*)d_out;         // Q bf16 (8 MB), dead before final GEMM
  USH* xb = (USH*)d_out + 4194304;     // x bf16 (8 MB), dead before final GEMM

  transpose_w<<<dim3(16, 16, 4), dim3(32, 8), 0, stream>>>(Wq, Wk, Wv, Wo, wT);
  cvt_x<<<2048, 256, 0, stream>>>(x, xb);
  gemm_bias<1><<<dim3(64, 4, 3), 256, 0, stream>>>(xb, wT, bq, bk, bv,
                                                   qscratch, kv, nullptr);
  attn<<<dim3(32, 16), 256, 0, stream>>>(qscratch, kv, att);
  gemm_bias<0><<<dim3(64, 4, 1), 256, 0, stream>>>(att, wT + 3 * 262144, bo, bo, bo,
                                                   nullptr, nullptr, outF);
}